// Round 4
// baseline (190.032 us; speedup 1.0000x reference)
//
#include <hip/hip_runtime.h>
#include <math.h>

#define KS    15
#define HALF  7
#define NORI  8
#define HW    256
#define TW    64
#define TH    64
#define WROW  48                 // tile row stride in words (96 bf16 cols)
#define RT    80                 // tile rows staged
#define TWORDS (RT * WROW)       // 3840 words per copy
#define TB1   (TWORDS + 8)       // copy-1 base: +8 word pad -> +8 bank shift
#define XSTR  140                // xsum row stride in words (16B aligned)

typedef __attribute__((ext_vector_type(8))) short  short8;
typedef __attribute__((ext_vector_type(4))) float  floatx4;

union FragU { uint4 u4; short8 s8; };

__device__ __forceinline__ ushort f2bf(float f) {
    union { float f; uint u; } a; a.f = f;
    return (ushort)((a.u + 0x7FFFu + ((a.u >> 16) & 1u)) >> 16);
}
__device__ __forceinline__ uint pack2(float lo, float hi) {
    return (uint)f2bf(lo) | ((uint)f2bf(hi) << 16);
}

// ---------------------------------------------------------------------------
// Pass 1: channel-sum -> bf16 xsum rows (word w covers cols 2w-8, 2w-7;
// words 0..3 and 132..139 are zero guards). Block (0,0) also builds weights.
// ---------------------------------------------------------------------------
__global__ __launch_bounds__(256) void gabor_pre(
    const float* __restrict__ x,
    const float* __restrict__ theta, const float* __restrict__ sigma,
    const float* __restrict__ lambd, const float* __restrict__ gamma,
    const float* __restrict__ psi,
    uint* __restrict__ xs, ushort* __restrict__ kw)
{
    const int tid = threadIdx.x;
    const int rg  = blockIdx.x;        // row group: 32 rows
    const int img = blockIdx.y;
    const float* xim = x + (size_t)img * 3 * HW * HW;

    // zero guard words (12 per row x 32 rows = 384)
    if (tid < 384) {
        const int r = tid / 12, k = tid - r * 12;
        const int w = (k < 4) ? k : (128 + k);          // 0..3, 132..139
        xs[((size_t)(img * HW) + rg * 32 + r) * XSTR + w] = 0;
    }

    // main: 1024 slots (32 rows x 32 col-groups of 8)
    #pragma unroll
    for (int s = 0; s < 4; ++s) {
        const int slot = tid + s * 256;
        const int r = slot >> 5, j = slot & 31;
        const int h = rg * 32 + r;
        const float* xr = xim + h * HW + 8 * j;
        const float4 a0 = *(const float4*)&xr[0];
        const float4 b0 = *(const float4*)&xr[HW * HW];
        const float4 c0 = *(const float4*)&xr[2 * HW * HW];
        const float4 a1 = *(const float4*)&xr[4];
        const float4 b1 = *(const float4*)&xr[HW * HW + 4];
        const float4 c1 = *(const float4*)&xr[2 * HW * HW + 4];
        uint4 wv;
        wv.x = pack2(a0.x + b0.x + c0.x, a0.y + b0.y + c0.y);
        wv.y = pack2(a0.z + b0.z + c0.z, a0.w + b0.w + c0.w);
        wv.z = pack2(a1.x + b1.x + c1.x, a1.y + b1.y + c1.y);
        wv.w = pack2(a1.z + b1.z + c1.z, a1.w + b1.w + c1.w);
        *(uint4*)&xs[((size_t)(img * HW) + h) * XSTR + 4 + 4 * j] = wv;
    }

    // weights: one block only; wave w -> orientations 2w, 2w+1
    if (rg == 0 && img == 0) {
        for (int i = tid; i < NORI * 16 * 16; i += 256) kw[i] = 0;
        __syncthreads();
        const int lane = tid & 63;
        const int wave = tid >> 6;
        #pragma unroll 1
        for (int oo = 0; oo < 2; ++oo) {
            const int o = wave * 2 + oo;
            const float th = theta[o];
            const float sg = fmaxf(sigma[o], 1.0f);
            const float lb = fmaxf(lambd[o], 2.0f);
            const float gm = fminf(fmaxf(gamma[o], 0.1f), 1.0f);
            const float ps = psi[o];
            const float ct = cosf(th), st = sinf(th);
            const float inv_sg2 = 1.0f / (sg * sg);
            const float gm2 = gm * gm;
            const float wfreq = 6.283185307179586f / lb;

            float vals[4];
            float sum = 0.0f, sumsq = 0.0f;
            #pragma unroll
            for (int j = 0; j < 4; ++j) {
                const int t = lane + j * 64;
                float v = 0.0f;
                if (t < KS * KS) {
                    const int ky = t / KS, kx = t % KS;
                    const float yg = (float)(ky - HALF);
                    const float xg = (float)(kx - HALF);
                    const float x_th =  xg * ct + yg * st;
                    const float y_th = -xg * st + yg * ct;
                    const float g = expf(-0.5f * (x_th * x_th + gm2 * y_th * y_th) * inv_sg2);
                    v = g * cosf(wfreq * x_th + ps);
                    sum += v; sumsq += v * v;
                }
                vals[j] = v;
            }
            #pragma unroll
            for (int off = 32; off > 0; off >>= 1) {
                sum   += __shfl_down(sum,   off);
                sumsq += __shfl_down(sumsq, off);
            }
            sum = __shfl(sum, 0); sumsq = __shfl(sumsq, 0);
            const float nn   = (float)(KS * KS);
            const float mean = sum / nn;
            const float var  = (sumsq - sum * sum / nn) / (nn - 1.0f);
            const float inv  = 1.0f / (sqrtf(var) + 1e-8f);
            #pragma unroll
            for (int j = 0; j < 4; ++j) {
                const int t = lane + j * 64;
                if (t < KS * KS) {
                    const int ky = t / KS, kx = t % KS;
                    kw[(o * 16 + ky) * 16 + kx] = f2bf((vals[j] - mean) * inv);
                }
            }
        }
    }
}

// ---------------------------------------------------------------------------
// Pass 2: MFMA conv. Staging = pure copy from xsum (both shifted copies from
// one aligned 5-word read). MFMA loop identical to validated round-3 kernel.
// ---------------------------------------------------------------------------
__global__ __launch_bounds__(256, 4) void gabor_conv(
    const uint* __restrict__ xs, const ushort* __restrict__ kw,
    float* __restrict__ out)
{
    __shared__ uint   tile[2 * TWORDS + 8];
    __shared__ ushort kwa[NORI * 16 * 16];

    const int tid  = threadIdx.x;
    const int img  = blockIdx.z;
    const int h0   = blockIdx.y * TH;
    const int w0   = blockIdx.x * TW;
    const int lane = tid & 63;
    const int wave = tid >> 6;

    // load weights LDS (2048 ushorts = 1024 words)
    {
        const uint* kw32 = (const uint*)kw;
        uint* kl32 = (uint*)kwa;
        #pragma unroll
        for (int i = 0; i < 4; ++i) kl32[tid + i * 256] = kw32[tid + i * 256];
    }

    // stage tile: 80 rows x 10 slots of 4 words (words 0..39 of each copy;
    // fragment reads touch words <= 38 only)
    {
        const uint* xrow0 = xs + (size_t)(img * HW) * XSTR;
        const int wb = w0 >> 1;
        #pragma unroll
        for (int s = 0; s < 4; ++s) {
            const int slot = tid + s * 256;
            if (slot < 800) {
                const int r = slot / 10, j = slot - r * 10;
                const int h = h0 + r - HALF;
                uint A0 = 0, A1 = 0, A2 = 0, A3 = 0, A4 = 0;
                if (h >= 0 && h < HW) {
                    const uint* row = xrow0 + (size_t)h * XSTR;
                    const int base = wb + 4 * j;            // even, <=132
                    const uint4 q = *(const uint4*)&row[base];
                    A0 = q.x; A1 = q.y; A2 = q.z; A3 = q.w;
                    A4 = row[base + 4];
                }
                uint4 c0, c1;
                c0.x = __builtin_amdgcn_alignbit(A1, A0, 16);
                c0.y = __builtin_amdgcn_alignbit(A2, A1, 16);
                c0.z = __builtin_amdgcn_alignbit(A3, A2, 16);
                c0.w = __builtin_amdgcn_alignbit(A4, A3, 16);
                c1.x = A1; c1.y = A2; c1.z = A3; c1.w = A4;
                *(uint4*)&tile[r * WROW + 4 * j]       = c0;   // odd-start copy
                *(uint4*)&tile[TB1 + r * WROW + 4 * j] = c1;   // even-start copy
            }
        }
    }
    __syncthreads();

    // ---- MFMA main loop: packed A (rows 0-7 = ori, rows 8-15 = ori shifted 1 ky) ----
    const int q   = lane >> 4;
    const int n   = lane & 15;
    const int qh  = q >> 1;
    const int kx0 = 8 * (q & 1);
    const int o   = n & 7;
    const int p   = n >> 3;

    short8 afrag[8];
    #pragma unroll
    for (int c = 0; c < 8; ++c) {
        const int kyi = (2 * c + qh - p) & 15;   // -1 wraps to 15 (zero row)
        afrag[c] = *reinterpret_cast<const short8*>(&kwa[(o * 16 + kyi) * 16 + kx0]);
    }

    const int pc   = wave * 16;
    const int col0 = pc + n + kx0;
    const uint cbase = (uint)((col0 & 1) * TB1 + (col0 >> 1));

    #pragma unroll 1
    for (int it = 0; it < 4; ++it) {
        const int pr0 = it * 16;
        floatx4 acc[8];
        #pragma unroll
        for (int i = 0; i < 8; ++i) acc[i] = (floatx4){0, 0, 0, 0};

        const uint rb = cbase + (uint)((pr0 + qh) * WROW);
        #pragma unroll
        for (int t = 0; t < 15; ++t) {
            const uint oe = rb + (uint)(2 * t * WROW);
            FragU f;
            f.u4.x = tile[oe];     f.u4.y = tile[oe + 1];
            f.u4.z = tile[oe + 2]; f.u4.w = tile[oe + 3];
            #pragma unroll
            for (int i = 0; i < 8; ++i) {
                if (t - i >= 0 && t - i < 8)
                    acc[i] = __builtin_amdgcn_mfma_f32_16x16x32_bf16(afrag[t - i], f.s8, acc[i], 0, 0, 0);
            }
        }

        const int wcol = w0 + pc + n;
        #pragma unroll
        for (int i = 0; i < 8; ++i) {
            const int H = h0 + pr0 + 2 * i;
            #pragma unroll
            for (int reg = 0; reg < 4; ++reg) {
                const int m  = q * 4 + reg;
                const int om = m & 7, pm = m >> 3;
                out[(((size_t)img * NORI + om) << 16) + ((size_t)(H + pm) << 8) + wcol] = acc[i][reg];
            }
        }
    }
}

extern "C" void kernel_launch(void* const* d_in, const int* in_sizes, int n_in,
                              void* d_out, int out_size, void* d_ws, size_t ws_size,
                              hipStream_t stream) {
    const float* x     = (const float*)d_in[0];
    const float* theta = (const float*)d_in[1];
    const float* sigma = (const float*)d_in[2];
    const float* lambd = (const float*)d_in[3];
    const float* gamma = (const float*)d_in[4];
    const float* psi   = (const float*)d_in[5];
    float* out = (float*)d_out;

    ushort* kw = (ushort*)d_ws;                        // 4 KB weights
    uint*   xs = (uint*)((char*)d_ws + 4096);          // 64*256*140 words = 9.17 MB

    gabor_pre<<<dim3(8, 64), 256, 0, stream>>>(x, theta, sigma, lambd, gamma, psi, xs, kw);
    gabor_conv<<<dim3(HW / TW, HW / TH, 64), 256, 0, stream>>>(xs, kw, out);
}